// Round 6
// baseline (900.171 us; speedup 1.0000x reference)
//
#include <hip/hip_runtime.h>

// B=16, T=256, C=6, E=512, H=8, hd=64.
// Inputs fp32; OUTPUT fp32. Compute in bf16 MFMA; biases added in fp32.
//
// Round 10: fused qkv_attn with LDS footprint 80 KB -> 56 KB so 2 blocks/CU
// ACTUALLY fit (round 9's 2x81920 = exact 160 KB fit was rejected by the
// scheduler; occupancy stayed 1 block/CU). K/V are staged to LDS in TWO
// 128-key passes sourced from the block's own accumulators (round-0
// super-chunk structure): Ks 16 KB + Vts 16 KB + Qs 16 KB = 48 KB attn
// footprint, staging 2x28 KB = 56 KB aliased on top. Chunk order per
// accumulator stays ascending -> bit-identical numerics.

typedef unsigned short u16;
typedef short bf16x8 __attribute__((ext_vector_type(8)));   // 8 bf16 = 4 VGPRs
typedef float f32x4 __attribute__((ext_vector_type(4)));
typedef u16 u16x4 __attribute__((ext_vector_type(4)));

#define MFMA16(a, b, c) __builtin_amdgcn_mfma_f32_16x16x32_bf16((a), (b), (c), 0, 0, 0)

__device__ __forceinline__ u16 f2b(float f) {
  union { float f; unsigned u; } v; v.f = f;
  unsigned r = v.u + 0x7fffu + ((v.u >> 16) & 1u);   // RNE (finite inputs)
  return (u16)(r >> 16);
}
__device__ __forceinline__ void gl_lds16(const void* g, void* l) {
  __builtin_amdgcn_global_load_lds(
      (const __attribute__((address_space(1))) void*)g,
      (__attribute__((address_space(3))) void*)l, 16, 0, 0);
}

// ---------------------------------------------------------------------------
// fp32 -> bf16 converters
// ---------------------------------------------------------------------------
__global__ void cvt_w(const float* W0, const float* W1, const float* W2,
                      const float* W3, u16* dst) {
  const float* src = (blockIdx.y == 0) ? W0 : (blockIdx.y == 1) ? W1
                   : (blockIdx.y == 2) ? W2 : W3;
  const int idx = (blockIdx.x * 256 + threadIdx.x) * 4;
  f32x4 v = *(const f32x4*)(src + idx);
  u16x4 o; o.x = f2b(v.x); o.y = f2b(v.y); o.z = f2b(v.z); o.w = f2b(v.w);
  *(u16x4*)(dst + (size_t)blockIdx.y * 262144 + idx) = o;
}

__global__ void cvt_x(const float* __restrict__ src, u16* __restrict__ dst) {
  const size_t idx = ((size_t)blockIdx.x * 256 + threadIdx.x) * 4;
  f32x4 v = *(const f32x4*)(src + idx);
  u16x4 o; o.x = f2b(v.x); o.y = f2b(v.y); o.z = f2b(v.z); o.w = f2b(v.w);
  *(u16x4*)(dst + idx) = o;
}

// ---------------------------------------------------------------------------
// Fused QKV + causal attention.  One block per (b,h,c); 512 thr = 8 waves.
// Wave w owns t-tiles {w, 15-w}.  LDS = 56 KB total (2 blocks/CU):
//   Phase 3 (two 128-key passes):
//     bytes [    0, 16384)  Ks  128 rows x 128 B  (XOR-swizzled)
//     bytes [16384, 32768)  Vts  64 rows x 256 B  (V^T, XOR-swizzled)
//     bytes [32768, 49152)  Qs   8 waves x 16 rows x 128 B (Q then P scratch)
//   Phase 1 staging: 2 x 28 KB at [0, 57344), aliases everything (disjoint
//   in time, barrier-separated).
// ---------------------------------------------------------------------------
#define STAGE(k, bi) do { \
  _Pragma("unroll") \
  for (int j_ = 0; j_ < 4; ++j_) \
    if (j_ < 3 || tid < 256) \
      gl_lds16(gsrc[j_] + (k) * 64, Sb + (bi) * 28672 + fl[j_]); \
} while (0)

__global__ __launch_bounds__(512, 4) void qkv_attn(
    const u16* __restrict__ xbf, const u16* __restrict__ wbf,
    const float* __restrict__ bq, const float* __restrict__ bk,
    const float* __restrict__ bv, u16* __restrict__ y_ws)
{
  const int blk = blockIdx.x;            // (b*8 + h)*6 + c  (b slab-local)
  const int b   = blk / 48;
  const int h   = (blk / 6) % 8;
  const int c   = blk % 6;

  __shared__ u16 LDS[28672];             // 56 KB
  char* Ksb  = (char*)LDS;               // Ks base   (16 KB)
  char* Vtsb = (char*)LDS + 16384;       // Vts base  (16 KB)
  char* Sb   = (char*)LDS;               // staging base (aliases all)

  const int tid  = threadIdx.x;
  const int lane = tid & 63;
  const int wv   = tid >> 6;
  const int r    = lane & 15;
  const int qd   = lane >> 4;
  const int tiles[2] = { wv, 15 - wv };
  char* Qw = (char*)LDS + 32768 + wv * 2048;   // per-wave 16 x 128 B

  // ---- staging source pointers (round-0 chunk swizzle: stored chunk q holds
  // global chunk (q - row>>1)&3; read side uses (qd + row>>1)&3) ----
  const char* gsrc[4]; int fl[4];
  #pragma unroll
  for (int j = 0; j < 4; ++j) {
    const int idx  = j * 512 + tid;
    const int flat = idx * 16;
    const int row  = flat >> 6;                       // 64 B per row
    const int gc   = (((flat >> 4) & 3) - (row >> 1)) & 3;
    fl[j] = flat;
    if (row < 256) {
      gsrc[j] = (const char*)xbf +
                ((size_t)(b * 256 + row) * 6 + c) * 1024 + gc * 16;
    } else {
      const int wr  = row - 256;
      const int tau = (wr >> 6) & 3;                  // masked for inactive lanes
      const int n   = wr & 63;
      gsrc[j] = (const char*)wbf + (size_t)tau * 524288 +
                (size_t)(h * 64 + n) * 1024 + gc * 16;
    }
  }

  // fragment LDS byte offsets within one staging buffer (loop-invariant)
  int aoff[2], boff[3][4];
  #pragma unroll
  for (int ti = 0; ti < 2; ++ti) {
    const int row = tiles[ti] * 16 + r;
    aoff[ti] = row * 64 + ((qd + (row >> 1)) & 3) * 16;
  }
  #pragma unroll
  for (int tau = 0; tau < 3; ++tau)
    #pragma unroll
    for (int nt = 0; nt < 4; ++nt) {
      const int row = 256 + tau * 64 + nt * 16 + r;
      boff[tau][nt] = row * 64 + ((qd + (row >> 1)) & 3) * 16;
    }

  f32x4 acc[3][2][4] = {};   // [q,k,v][tile][ntile]

  // ---- Phase 1: GEMM over K=512, BK=32, double-buffered ----
  STAGE(0, 0);
  __syncthreads();

  #pragma unroll 2
  for (int kt = 0; kt < 16; ++kt) {
    const int bi = kt & 1;
    if (kt < 15) STAGE(kt + 1, bi ^ 1);

    bf16x8 af[2], bfr[3][4];
    #pragma unroll
    for (int ti = 0; ti < 2; ++ti)
      af[ti] = *(const bf16x8*)(Sb + bi * 28672 + aoff[ti]);
    #pragma unroll
    for (int tau = 0; tau < 3; ++tau)
      #pragma unroll
      for (int nt = 0; nt < 4; ++nt)
        bfr[tau][nt] = *(const bf16x8*)(Sb + bi * 28672 + boff[tau][nt]);

    #pragma unroll
    for (int tau = 0; tau < 3; ++tau)
      #pragma unroll
      for (int ti = 0; ti < 2; ++ti)
        #pragma unroll
        for (int nt = 0; nt < 4; ++nt)
          acc[tau][ti][nt] = MFMA16(af[ti], bfr[tau][nt], acc[tau][ti][nt]);

    __syncthreads();   // drains staged kt+1; guards buffer reuse
  }
  // Phase-1 done: staging region free for Ks/Vts/Qs.

  // ---- biases (fp32) ----
  float bqv[4], bkv[4], bvv[4];
  #pragma unroll
  for (int nt = 0; nt < 4; ++nt) {
    const int col = h * 64 + nt * 16 + r;
    bqv[nt] = bq[col]; bkv[nt] = bk[col]; bvv[nt] = bv[col];
  }

  const int lo0 = ( qd      ^ (r & 7)) << 4;   // K/Q/P granule, kc=0
  const int lo1 = ((4 + qd) ^ (r & 7)) << 4;   // kc=1

  f32x4 o_acc[2][4] = {};
  float l_acc[2][4] = {{0.f,0.f,0.f,0.f},{0.f,0.f,0.f,0.f}};

  // ---- Phases 2+3: two 128-key passes ----
  for (int sc = 0; sc < 2; ++sc) {
    if (sc) __syncthreads();           // pass-0 reads done before overwrite

    // write this pass's K/V chunk from registers (tile tiles[sc])
    #pragma unroll
    for (int nt = 0; nt < 4; ++nt)
      #pragma unroll
      for (int rr = 0; rr < 4; ++rr) {
        const int tl = tiles[sc] * 16 + qd * 4 + rr - sc * 128;   // 0..127
        // Ks[tl][nt*16+r], 128-B rows, granule ^= tl&7
        const int kb = tl * 128 +
            (((nt * 2 + (r >> 3)) ^ (tl & 7)) << 4) + (r & 7) * 2;
        *(u16*)(Ksb + kb) = f2b(acc[1][sc][nt][rr] + bkv[nt]);
        // Vts[d = nt*16+r][t = tl], 256-B rows, granule ^= d&7 (= r&7)
        const int vb = (nt * 16 + r) * 256 +
            (((tl >> 3) ^ (r & 7)) << 4) + (tl & 7) * 2;
        *(u16*)(Vtsb + vb) = f2b(acc[2][sc][nt][rr] + bvv[nt]);
      }
    __syncthreads();

    // attention against this pass's keys
    #pragma unroll
    for (int ti = 0; ti < 2; ++ti) {
      if (sc == 1 && ti == 0) continue;   // q-tiles 0..7 complete in pass 0
      const int mt  = tiles[ti];
      const int i0  = mt * 16;
      const int nch = (mt >> 2) + 1;      // total 64-chunks this tile needs

      // Q bounce through per-wave scratch (wave-local; DS ops in-order)
      #pragma unroll
      for (int nt = 0; nt < 4; ++nt)
        #pragma unroll
        for (int rr = 0; rr < 4; ++rr) {
          const int prow = qd * 4 + rr;
          const int qb = prow * 128 +
              (((nt * 2 + (r >> 3)) ^ (prow & 7)) << 4) + (r & 7) * 2;
          *(u16*)(Qw + qb) = f2b(acc[0][ti][nt][rr] + bqv[nt]);
        }
      asm volatile("s_waitcnt lgkmcnt(0)" ::: "memory");

      bf16x8 qf[2];
      qf[0] = *(const bf16x8*)(Qw + r * 128 + lo0);
      qf[1] = *(const bf16x8*)(Qw + r * 128 + lo1);
      asm volatile("s_waitcnt lgkmcnt(0)" ::: "memory");

      #pragma unroll
      for (int jcl = 0; jcl < 2; ++jcl) {
        const int jcg = sc * 2 + jcl;
        if (jcg >= nch) continue;         // wave-uniform skip
        const int j0l = jcl * 64;         // key offset within this pass
        const int j0g = jcg * 64;         // global key offset (causal mask)

        f32x4 s[4] = {};
        #pragma unroll
        for (int nt = 0; nt < 4; ++nt) {
          const int krow = j0l + nt * 16 + r;
          bf16x8 kf0 = *(const bf16x8*)(Ksb + krow * 128 + lo0);
          s[nt] = MFMA16(qf[0], kf0, s[nt]);
          bf16x8 kf1 = *(const bf16x8*)(Ksb + krow * 128 + lo1);
          s[nt] = MFMA16(qf[1], kf1, s[nt]);
        }

        #pragma unroll
        for (int nt = 0; nt < 4; ++nt)
          #pragma unroll
          for (int rr = 0; rr < 4; ++rr) {
            const int i = i0 + qd * 4 + rr;
            const int j = j0g + nt * 16 + r;
            float p = __builtin_exp2f(fminf(s[nt][rr], 500.f) *
                                      0.1803368801111244f);  // *(1/8)*log2(e)
            if (j > i) p = 0.f;
            l_acc[ti][rr] += p;
            const int prow = qd * 4 + rr;
            const int pb = prow * 128 +
                (((nt * 2 + (r >> 3)) ^ (prow & 7)) << 4) + (r & 7) * 2;
            *(u16*)(Qw + pb) = f2b(p);
          }
        asm volatile("s_waitcnt lgkmcnt(0)" ::: "memory");

        bf16x8 pf[2];
        pf[0] = *(const bf16x8*)(Qw + r * 128 + lo0);
        pf[1] = *(const bf16x8*)(Qw + r * 128 + lo1);
        #pragma unroll
        for (int ntd = 0; ntd < 4; ++ntd) {
          const int vrow = ntd * 16 + r;
          bf16x8 vf0 = *(const bf16x8*)(Vtsb + vrow * 256 +
              ((((j0l >> 3) + qd) ^ (r & 7)) << 4));
          o_acc[ti][ntd] = MFMA16(pf[0], vf0, o_acc[ti][ntd]);
          bf16x8 vf1 = *(const bf16x8*)(Vtsb + vrow * 256 +
              ((((j0l >> 3) + 4 + qd) ^ (r & 7)) << 4));
          o_acc[ti][ntd] = MFMA16(pf[1], vf1, o_acc[ti][ntd]);
        }
      }
    }
  }

  // ---- output: y layout [b][t][h][c][d] (faithful to the torch reshape) ----
  const size_t obase = ((size_t)b * 256) * 3072 + h * 384 + c * 64;
  #pragma unroll
  for (int ti = 0; ti < 2; ++ti) {
    const int i0 = tiles[ti] * 16;
    float linv[4];
    #pragma unroll
    for (int rr = 0; rr < 4; ++rr) {
      float sum = l_acc[ti][rr];
      sum += __shfl_xor(sum, 1, 16);
      sum += __shfl_xor(sum, 2, 16);
      sum += __shfl_xor(sum, 4, 16);
      sum += __shfl_xor(sum, 8, 16);
      linv[rr] = 1.f / sum;
    }
    #pragma unroll
    for (int ntd = 0; ntd < 4; ++ntd)
      #pragma unroll
      for (int rr = 0; rr < 4; ++rr) {
        const int t = i0 + qd * 4 + rr;
        const int d = ntd * 16 + r;
        y_ws[obase + (size_t)t * 3072 + d] = f2b(o_acc[ti][ntd][rr] * linv[rr]);
      }
  }
}

// ---------------------------------------------------------------------------
// BT-GEMM (round-0 verbatim, used for the output projection only).
// ---------------------------------------------------------------------------
__global__ __launch_bounds__(256, 3) void gemm_bt(
    const u16* __restrict__ A,
    const u16* W0, const u16* W1, const u16* W2,
    const float* bs0, const float* bs1, const float* bs2,
    u16* O0, u16* O1, u16* O2,
    float* OF,
    int qkv_mode)
{
  const int z = blockIdx.z;
  const u16* W    = (z == 0) ? W0 : (z == 1) ? W1 : W2;
  const float* bs = (z == 0) ? bs0 : (z == 1) ? bs1 : bs2;
  u16* O          = (z == 0) ? O0 : (z == 1) ? O1 : O2;

  const int m0 = blockIdx.x * 128;
  const int n0 = blockIdx.y * 128;

  __shared__ u16 As[128 * 32];   // 8 KB, 64B rows, chunk swizzle (q + (row>>1)) & 3
  __shared__ u16 Bs[128 * 32];

  const int tid  = threadIdx.x;
  const int lane = tid & 63;
  const int wv   = tid >> 6;
  const int r    = lane & 15;
  const int qd   = lane >> 4;
  const int wm   = (wv & 1) * 64;
  const int wn   = (wv >> 1) * 64;

  f32x4 acc[4][4] = {};

  for (int k0 = 0; k0 < 512; k0 += 32) {
    __syncthreads();
    #pragma unroll
    for (int it = 0; it < 2; ++it) {
      const int flat = (it * 256 + tid) * 16;       // byte offset in 8KB tile
      const int row  = flat >> 6;                   // 64 B per row
      const int swc  = (flat >> 4) & 3;
      const int gc   = (swc - (row >> 1)) & 3;      // un-swizzle for global side
      gl_lds16((const char*)A + (size_t)(m0 + row) * 1024 + k0 * 2 + gc * 16,
               (char*)As + flat);
      gl_lds16((const char*)W + (size_t)(n0 + row) * 1024 + k0 * 2 + gc * 16,
               (char*)Bs + flat);
    }
    __syncthreads();

    bf16x8 af[4], bf[4];
    #pragma unroll
    for (int mt = 0; mt < 4; ++mt) {
      const int row = wm + mt * 16 + r;
      const int sw  = (qd + (row >> 1)) & 3;
      af[mt] = *(const bf16x8*)((const char*)As + row * 64 + sw * 16);
    }
    #pragma unroll
    for (int nt = 0; nt < 4; ++nt) {
      const int row = wn + nt * 16 + r;
      const int sw  = (qd + (row >> 1)) & 3;
      bf[nt] = *(const bf16x8*)((const char*)Bs + row * 64 + sw * 16);
    }
    #pragma unroll
    for (int mt = 0; mt < 4; ++mt)
      #pragma unroll
      for (int nt = 0; nt < 4; ++nt)
        acc[mt][nt] = MFMA16(af[mt], bf[nt], acc[mt][nt]);
  }

  float bv[4];
  #pragma unroll
  for (int nt = 0; nt < 4; ++nt) bv[nt] = bs[n0 + wn + nt * 16 + r];

  if (qkv_mode) {
    #pragma unroll
    for (int mt = 0; mt < 4; ++mt) {
      #pragma unroll
      for (int rr = 0; rr < 4; ++rr) {
        const int m   = m0 + wm + mt * 16 + qd * 4 + rr;   // (b*T+t)*C + c
        const int b   = m / 1536;
        const int rem = m - b * 1536;
        const int t   = rem / 6;
        const int c   = rem - t * 6;
        #pragma unroll
        for (int nt = 0; nt < 4; ++nt) {
          const int f = n0 + wn + nt * 16 + r;             // h*64 + d
          const int hh = f >> 6;
          const int d = f & 63;
          const size_t addr = ((((size_t)b * 8 + hh) * 6 + c) * 256 + t) * 64 + d;
          O[addr] = f2b(acc[mt][nt][rr] + bv[nt]);
        }
      }
    }
  } else {
    #pragma unroll
    for (int mt = 0; mt < 4; ++mt) {
      #pragma unroll
      for (int rr = 0; rr < 4; ++rr) {
        const int m = m0 + wm + mt * 16 + qd * 4 + rr;
        #pragma unroll
        for (int nt = 0; nt < 4; ++nt) {
          const int f = n0 + wn + nt * 16 + r;
          OF[(size_t)m * 512 + f] = acc[mt][nt][rr] + bv[nt];   // fp32 output
        }
      }
    }
  }
}

// ---------------------------------------------------------------------------
extern "C" void kernel_launch(void* const* d_in, const int* in_sizes, int n_in,
                              void* d_out, int out_size, void* d_ws, size_t ws_size,
                              hipStream_t stream) {
  const float* x  = (const float*)d_in[0];
  const float* Wq = (const float*)d_in[1];
  const float* bq = (const float*)d_in[2];
  const float* Wk = (const float*)d_in[3];
  const float* bk = (const float*)d_in[4];
  const float* Wv = (const float*)d_in[5];
  const float* bv = (const float*)d_in[6];
  const float* Wp = (const float*)d_in[7];
  const float* bp = (const float*)d_in[8];
  float* out = (float*)d_out;                        // fp32 output

  const size_t PER_B = 256 * 6 * 512;       // 786432 elems per tensor per batch
  const size_t WSEG  = 4 * 262144;          // converted weights: Wq,Wk,Wv,Wp

  int NB = 16;
  while (NB > 1 && (WSEG + (size_t)2 * NB * PER_B) * 2 > ws_size) NB >>= 1;

  u16* wbf = (u16*)d_ws;                    // Wq | Wk | Wv | Wp (bf16)
  u16* Wpb = wbf + 3 * 262144;

  const size_t slab = (size_t)NB * PER_B;
  u16* xbf  = wbf + WSEG;
  u16* y_ws = xbf + slab;

  cvt_w<<<dim3(256, 4), 256, 0, stream>>>(Wq, Wk, Wv, Wp, wbf);

  const int nslab = 16 / NB;
  for (int s = 0; s < nslab; ++s) {
    const float* x_s  = x   + (size_t)s * NB * PER_B;
    float*      out_s = out + (size_t)s * NB * PER_B;
    cvt_x<<<dim3(NB * 768), 256, 0, stream>>>(x_s, xbf);
    qkv_attn<<<dim3(NB * 48), 512, 0, stream>>>(xbf, wbf, bq, bk, bv, y_ws);
    gemm_bt<<<dim3(NB * 12, 4, 1), 256, 0, stream>>>(
        y_ws, Wpb, Wpb, Wpb, bp, bp, bp, nullptr, nullptr, nullptr, out_s, 0);
  }
}

// Round 7
// 880.016 us; speedup vs baseline: 1.0229x; 1.0229x over previous
//
#include <hip/hip_runtime.h>

// B=16, T=256, C=6, E=512, H=8, hd=64.
// Inputs fp32; OUTPUT fp32. Compute in bf16 MFMA; biases added in fp32.
//
// Round 11: round-10 kernel (56 KB LDS, two 128-key passes) with the launch
// bound FIXED back to (512,2).  Round 10's __launch_bounds__(512,4) capped
// VGPR at 64 -> full accumulator spill (FETCH 1.4 GB, WRITE 2.5 GB scratch
// traffic, 12x slowdown).  With (512,2): VGPR ~76-96 < 128 -> HW allows
// 4 waves/SIMD = 16 waves/CU = 2 blocks/CU; 2 x 57344 B LDS fits 160 KB.

typedef unsigned short u16;
typedef short bf16x8 __attribute__((ext_vector_type(8)));   // 8 bf16 = 4 VGPRs
typedef float f32x4 __attribute__((ext_vector_type(4)));
typedef u16 u16x4 __attribute__((ext_vector_type(4)));

#define MFMA16(a, b, c) __builtin_amdgcn_mfma_f32_16x16x32_bf16((a), (b), (c), 0, 0, 0)

__device__ __forceinline__ u16 f2b(float f) {
  union { float f; unsigned u; } v; v.f = f;
  unsigned r = v.u + 0x7fffu + ((v.u >> 16) & 1u);   // RNE (finite inputs)
  return (u16)(r >> 16);
}
__device__ __forceinline__ void gl_lds16(const void* g, void* l) {
  __builtin_amdgcn_global_load_lds(
      (const __attribute__((address_space(1))) void*)g,
      (__attribute__((address_space(3))) void*)l, 16, 0, 0);
}

// ---------------------------------------------------------------------------
// fp32 -> bf16 converters
// ---------------------------------------------------------------------------
__global__ void cvt_w(const float* W0, const float* W1, const float* W2,
                      const float* W3, u16* dst) {
  const float* src = (blockIdx.y == 0) ? W0 : (blockIdx.y == 1) ? W1
                   : (blockIdx.y == 2) ? W2 : W3;
  const int idx = (blockIdx.x * 256 + threadIdx.x) * 4;
  f32x4 v = *(const f32x4*)(src + idx);
  u16x4 o; o.x = f2b(v.x); o.y = f2b(v.y); o.z = f2b(v.z); o.w = f2b(v.w);
  *(u16x4*)(dst + (size_t)blockIdx.y * 262144 + idx) = o;
}

__global__ void cvt_x(const float* __restrict__ src, u16* __restrict__ dst) {
  const size_t idx = ((size_t)blockIdx.x * 256 + threadIdx.x) * 4;
  f32x4 v = *(const f32x4*)(src + idx);
  u16x4 o; o.x = f2b(v.x); o.y = f2b(v.y); o.z = f2b(v.z); o.w = f2b(v.w);
  *(u16x4*)(dst + idx) = o;
}

// ---------------------------------------------------------------------------
// Fused QKV + causal attention.  One block per (b,h,c); 512 thr = 8 waves.
// Wave w owns t-tiles {w, 15-w}.  LDS = 56 KB total (2 blocks/CU):
//   Phase 3 (two 128-key passes):
//     bytes [    0, 16384)  Ks  128 rows x 128 B  (XOR-swizzled)
//     bytes [16384, 32768)  Vts  64 rows x 256 B  (V^T, XOR-swizzled)
//     bytes [32768, 49152)  Qs   8 waves x 16 rows x 128 B (Q then P scratch)
//   Phase 1 staging: 2 x 28 KB at [0, 57344), aliases everything (disjoint
//   in time, barrier-separated).
// ---------------------------------------------------------------------------
#define STAGE(k, bi) do { \
  _Pragma("unroll") \
  for (int j_ = 0; j_ < 4; ++j_) \
    if (j_ < 3 || tid < 256) \
      gl_lds16(gsrc[j_] + (k) * 64, Sb + (bi) * 28672 + fl[j_]); \
} while (0)

__global__ __launch_bounds__(512, 2) void qkv_attn(
    const u16* __restrict__ xbf, const u16* __restrict__ wbf,
    const float* __restrict__ bq, const float* __restrict__ bk,
    const float* __restrict__ bv, u16* __restrict__ y_ws)
{
  const int blk = blockIdx.x;            // (b*8 + h)*6 + c  (b slab-local)
  const int b   = blk / 48;
  const int h   = (blk / 6) % 8;
  const int c   = blk % 6;

  __shared__ u16 LDS[28672];             // 56 KB
  char* Ksb  = (char*)LDS;               // Ks base   (16 KB)
  char* Vtsb = (char*)LDS + 16384;       // Vts base  (16 KB)
  char* Sb   = (char*)LDS;               // staging base (aliases all)

  const int tid  = threadIdx.x;
  const int lane = tid & 63;
  const int wv   = tid >> 6;
  const int r    = lane & 15;
  const int qd   = lane >> 4;
  const int tiles[2] = { wv, 15 - wv };
  char* Qw = (char*)LDS + 32768 + wv * 2048;   // per-wave 16 x 128 B

  // ---- staging source pointers (round-0 chunk swizzle: stored chunk q holds
  // global chunk (q - row>>1)&3; read side uses (qd + row>>1)&3) ----
  const char* gsrc[4]; int fl[4];
  #pragma unroll
  for (int j = 0; j < 4; ++j) {
    const int idx  = j * 512 + tid;
    const int flat = idx * 16;
    const int row  = flat >> 6;                       // 64 B per row
    const int gc   = (((flat >> 4) & 3) - (row >> 1)) & 3;
    fl[j] = flat;
    if (row < 256) {
      gsrc[j] = (const char*)xbf +
                ((size_t)(b * 256 + row) * 6 + c) * 1024 + gc * 16;
    } else {
      const int wr  = row - 256;
      const int tau = (wr >> 6) & 3;                  // masked for inactive lanes
      const int n   = wr & 63;
      gsrc[j] = (const char*)wbf + (size_t)tau * 524288 +
                (size_t)(h * 64 + n) * 1024 + gc * 16;
    }
  }

  // fragment LDS byte offsets within one staging buffer (loop-invariant)
  int aoff[2], boff[3][4];
  #pragma unroll
  for (int ti = 0; ti < 2; ++ti) {
    const int row = tiles[ti] * 16 + r;
    aoff[ti] = row * 64 + ((qd + (row >> 1)) & 3) * 16;
  }
  #pragma unroll
  for (int tau = 0; tau < 3; ++tau)
    #pragma unroll
    for (int nt = 0; nt < 4; ++nt) {
      const int row = 256 + tau * 64 + nt * 16 + r;
      boff[tau][nt] = row * 64 + ((qd + (row >> 1)) & 3) * 16;
    }

  f32x4 acc[3][2][4] = {};   // [q,k,v][tile][ntile]

  // ---- Phase 1: GEMM over K=512, BK=32, double-buffered ----
  STAGE(0, 0);
  __syncthreads();

  #pragma unroll 2
  for (int kt = 0; kt < 16; ++kt) {
    const int bi = kt & 1;
    if (kt < 15) STAGE(kt + 1, bi ^ 1);

    bf16x8 af[2], bfr[3][4];
    #pragma unroll
    for (int ti = 0; ti < 2; ++ti)
      af[ti] = *(const bf16x8*)(Sb + bi * 28672 + aoff[ti]);
    #pragma unroll
    for (int tau = 0; tau < 3; ++tau)
      #pragma unroll
      for (int nt = 0; nt < 4; ++nt)
        bfr[tau][nt] = *(const bf16x8*)(Sb + bi * 28672 + boff[tau][nt]);

    #pragma unroll
    for (int tau = 0; tau < 3; ++tau)
      #pragma unroll
      for (int ti = 0; ti < 2; ++ti)
        #pragma unroll
        for (int nt = 0; nt < 4; ++nt)
          acc[tau][ti][nt] = MFMA16(af[ti], bfr[tau][nt], acc[tau][ti][nt]);

    __syncthreads();   // drains staged kt+1; guards buffer reuse
  }
  // Phase-1 done: staging region free for Ks/Vts/Qs.

  // ---- biases (fp32) ----
  float bqv[4], bkv[4], bvv[4];
  #pragma unroll
  for (int nt = 0; nt < 4; ++nt) {
    const int col = h * 64 + nt * 16 + r;
    bqv[nt] = bq[col]; bkv[nt] = bk[col]; bvv[nt] = bv[col];
  }

  const int lo0 = ( qd      ^ (r & 7)) << 4;   // K/Q/P granule, kc=0
  const int lo1 = ((4 + qd) ^ (r & 7)) << 4;   // kc=1

  f32x4 o_acc[2][4] = {};
  float l_acc[2][4] = {{0.f,0.f,0.f,0.f},{0.f,0.f,0.f,0.f}};

  // ---- Phases 2+3: two 128-key passes ----
  for (int sc = 0; sc < 2; ++sc) {
    if (sc) __syncthreads();           // pass-0 reads done before overwrite

    // write this pass's K/V chunk from registers (tile tiles[sc])
    #pragma unroll
    for (int nt = 0; nt < 4; ++nt)
      #pragma unroll
      for (int rr = 0; rr < 4; ++rr) {
        const int tl = tiles[sc] * 16 + qd * 4 + rr - sc * 128;   // 0..127
        // Ks[tl][nt*16+r], 128-B rows, granule ^= tl&7
        const int kb = tl * 128 +
            (((nt * 2 + (r >> 3)) ^ (tl & 7)) << 4) + (r & 7) * 2;
        *(u16*)(Ksb + kb) = f2b(acc[1][sc][nt][rr] + bkv[nt]);
        // Vts[d = nt*16+r][t = tl], 256-B rows, granule ^= d&7 (= r&7)
        const int vb = (nt * 16 + r) * 256 +
            (((tl >> 3) ^ (r & 7)) << 4) + (tl & 7) * 2;
        *(u16*)(Vtsb + vb) = f2b(acc[2][sc][nt][rr] + bvv[nt]);
      }
    __syncthreads();

    // attention against this pass's keys
    #pragma unroll
    for (int ti = 0; ti < 2; ++ti) {
      if (sc == 1 && ti == 0) continue;   // q-tiles 0..7 complete in pass 0
      const int mt  = tiles[ti];
      const int i0  = mt * 16;
      const int nch = (mt >> 2) + 1;      // total 64-chunks this tile needs

      // Q bounce through per-wave scratch (wave-local; DS ops in-order)
      #pragma unroll
      for (int nt = 0; nt < 4; ++nt)
        #pragma unroll
        for (int rr = 0; rr < 4; ++rr) {
          const int prow = qd * 4 + rr;
          const int qb = prow * 128 +
              (((nt * 2 + (r >> 3)) ^ (prow & 7)) << 4) + (r & 7) * 2;
          *(u16*)(Qw + qb) = f2b(acc[0][ti][nt][rr] + bqv[nt]);
        }
      asm volatile("s_waitcnt lgkmcnt(0)" ::: "memory");

      bf16x8 qf[2];
      qf[0] = *(const bf16x8*)(Qw + r * 128 + lo0);
      qf[1] = *(const bf16x8*)(Qw + r * 128 + lo1);
      asm volatile("s_waitcnt lgkmcnt(0)" ::: "memory");

      #pragma unroll
      for (int jcl = 0; jcl < 2; ++jcl) {
        const int jcg = sc * 2 + jcl;
        if (jcg >= nch) continue;         // wave-uniform skip
        const int j0l = jcl * 64;         // key offset within this pass
        const int j0g = jcg * 64;         // global key offset (causal mask)

        f32x4 s[4] = {};
        #pragma unroll
        for (int nt = 0; nt < 4; ++nt) {
          const int krow = j0l + nt * 16 + r;
          bf16x8 kf0 = *(const bf16x8*)(Ksb + krow * 128 + lo0);
          s[nt] = MFMA16(qf[0], kf0, s[nt]);
          bf16x8 kf1 = *(const bf16x8*)(Ksb + krow * 128 + lo1);
          s[nt] = MFMA16(qf[1], kf1, s[nt]);
        }

        #pragma unroll
        for (int nt = 0; nt < 4; ++nt)
          #pragma unroll
          for (int rr = 0; rr < 4; ++rr) {
            const int i = i0 + qd * 4 + rr;
            const int j = j0g + nt * 16 + r;
            float p = __builtin_exp2f(fminf(s[nt][rr], 500.f) *
                                      0.1803368801111244f);  // *(1/8)*log2(e)
            if (j > i) p = 0.f;
            l_acc[ti][rr] += p;
            const int prow = qd * 4 + rr;
            const int pb = prow * 128 +
                (((nt * 2 + (r >> 3)) ^ (prow & 7)) << 4) + (r & 7) * 2;
            *(u16*)(Qw + pb) = f2b(p);
          }
        asm volatile("s_waitcnt lgkmcnt(0)" ::: "memory");

        bf16x8 pf[2];
        pf[0] = *(const bf16x8*)(Qw + r * 128 + lo0);
        pf[1] = *(const bf16x8*)(Qw + r * 128 + lo1);
        #pragma unroll
        for (int ntd = 0; ntd < 4; ++ntd) {
          const int vrow = ntd * 16 + r;
          bf16x8 vf0 = *(const bf16x8*)(Vtsb + vrow * 256 +
              ((((j0l >> 3) + qd) ^ (r & 7)) << 4));
          o_acc[ti][ntd] = MFMA16(pf[0], vf0, o_acc[ti][ntd]);
          bf16x8 vf1 = *(const bf16x8*)(Vtsb + vrow * 256 +
              ((((j0l >> 3) + 4 + qd) ^ (r & 7)) << 4));
          o_acc[ti][ntd] = MFMA16(pf[1], vf1, o_acc[ti][ntd]);
        }
      }
    }
  }

  // ---- output: y layout [b][t][h][c][d] (faithful to the torch reshape) ----
  const size_t obase = ((size_t)b * 256) * 3072 + h * 384 + c * 64;
  #pragma unroll
  for (int ti = 0; ti < 2; ++ti) {
    const int i0 = tiles[ti] * 16;
    float linv[4];
    #pragma unroll
    for (int rr = 0; rr < 4; ++rr) {
      float sum = l_acc[ti][rr];
      sum += __shfl_xor(sum, 1, 16);
      sum += __shfl_xor(sum, 2, 16);
      sum += __shfl_xor(sum, 4, 16);
      sum += __shfl_xor(sum, 8, 16);
      linv[rr] = 1.f / sum;
    }
    #pragma unroll
    for (int ntd = 0; ntd < 4; ++ntd)
      #pragma unroll
      for (int rr = 0; rr < 4; ++rr) {
        const int t = i0 + qd * 4 + rr;
        const int d = ntd * 16 + r;
        y_ws[obase + (size_t)t * 3072 + d] = f2b(o_acc[ti][ntd][rr] * linv[rr]);
      }
  }
}

// ---------------------------------------------------------------------------
// BT-GEMM (round-0 verbatim, used for the output projection only).
// ---------------------------------------------------------------------------
__global__ __launch_bounds__(256, 3) void gemm_bt(
    const u16* __restrict__ A,
    const u16* W0, const u16* W1, const u16* W2,
    const float* bs0, const float* bs1, const float* bs2,
    u16* O0, u16* O1, u16* O2,
    float* OF,
    int qkv_mode)
{
  const int z = blockIdx.z;
  const u16* W    = (z == 0) ? W0 : (z == 1) ? W1 : W2;
  const float* bs = (z == 0) ? bs0 : (z == 1) ? bs1 : bs2;
  u16* O          = (z == 0) ? O0 : (z == 1) ? O1 : O2;

  const int m0 = blockIdx.x * 128;
  const int n0 = blockIdx.y * 128;

  __shared__ u16 As[128 * 32];   // 8 KB, 64B rows, chunk swizzle (q + (row>>1)) & 3
  __shared__ u16 Bs[128 * 32];

  const int tid  = threadIdx.x;
  const int lane = tid & 63;
  const int wv   = tid >> 6;
  const int r    = lane & 15;
  const int qd   = lane >> 4;
  const int wm   = (wv & 1) * 64;
  const int wn   = (wv >> 1) * 64;

  f32x4 acc[4][4] = {};

  for (int k0 = 0; k0 < 512; k0 += 32) {
    __syncthreads();
    #pragma unroll
    for (int it = 0; it < 2; ++it) {
      const int flat = (it * 256 + tid) * 16;       // byte offset in 8KB tile
      const int row  = flat >> 6;                   // 64 B per row
      const int swc  = (flat >> 4) & 3;
      const int gc   = (swc - (row >> 1)) & 3;      // un-swizzle for global side
      gl_lds16((const char*)A + (size_t)(m0 + row) * 1024 + k0 * 2 + gc * 16,
               (char*)As + flat);
      gl_lds16((const char*)W + (size_t)(n0 + row) * 1024 + k0 * 2 + gc * 16,
               (char*)Bs + flat);
    }
    __syncthreads();

    bf16x8 af[4], bf[4];
    #pragma unroll
    for (int mt = 0; mt < 4; ++mt) {
      const int row = wm + mt * 16 + r;
      const int sw  = (qd + (row >> 1)) & 3;
      af[mt] = *(const bf16x8*)((const char*)As + row * 64 + sw * 16);
    }
    #pragma unroll
    for (int nt = 0; nt < 4; ++nt) {
      const int row = wn + nt * 16 + r;
      const int sw  = (qd + (row >> 1)) & 3;
      bf[nt] = *(const bf16x8*)((const char*)Bs + row * 64 + sw * 16);
    }
    #pragma unroll
    for (int mt = 0; mt < 4; ++mt)
      #pragma unroll
      for (int nt = 0; nt < 4; ++nt)
        acc[mt][nt] = MFMA16(af[mt], bf[nt], acc[mt][nt]);
  }

  float bv[4];
  #pragma unroll
  for (int nt = 0; nt < 4; ++nt) bv[nt] = bs[n0 + wn + nt * 16 + r];

  if (qkv_mode) {
    #pragma unroll
    for (int mt = 0; mt < 4; ++mt) {
      #pragma unroll
      for (int rr = 0; rr < 4; ++rr) {
        const int m   = m0 + wm + mt * 16 + qd * 4 + rr;   // (b*T+t)*C + c
        const int b   = m / 1536;
        const int rem = m - b * 1536;
        const int t   = rem / 6;
        const int c   = rem - t * 6;
        #pragma unroll
        for (int nt = 0; nt < 4; ++nt) {
          const int f = n0 + wn + nt * 16 + r;             // h*64 + d
          const int hh = f >> 6;
          const int d = f & 63;
          const size_t addr = ((((size_t)b * 8 + hh) * 6 + c) * 256 + t) * 64 + d;
          O[addr] = f2b(acc[mt][nt][rr] + bv[nt]);
        }
      }
    }
  } else {
    #pragma unroll
    for (int mt = 0; mt < 4; ++mt) {
      #pragma unroll
      for (int rr = 0; rr < 4; ++rr) {
        const int m = m0 + wm + mt * 16 + qd * 4 + rr;
        #pragma unroll
        for (int nt = 0; nt < 4; ++nt) {
          const int f = n0 + wn + nt * 16 + r;
          OF[(size_t)m * 512 + f] = acc[mt][nt][rr] + bv[nt];   // fp32 output
        }
      }
    }
  }
}

// ---------------------------------------------------------------------------
extern "C" void kernel_launch(void* const* d_in, const int* in_sizes, int n_in,
                              void* d_out, int out_size, void* d_ws, size_t ws_size,
                              hipStream_t stream) {
  const float* x  = (const float*)d_in[0];
  const float* Wq = (const float*)d_in[1];
  const float* bq = (const float*)d_in[2];
  const float* Wk = (const float*)d_in[3];
  const float* bk = (const float*)d_in[4];
  const float* Wv = (const float*)d_in[5];
  const float* bv = (const float*)d_in[6];
  const float* Wp = (const float*)d_in[7];
  const float* bp = (const float*)d_in[8];
  float* out = (float*)d_out;                        // fp32 output

  const size_t PER_B = 256 * 6 * 512;       // 786432 elems per tensor per batch
  const size_t WSEG  = 4 * 262144;          // converted weights: Wq,Wk,Wv,Wp

  int NB = 16;
  while (NB > 1 && (WSEG + (size_t)2 * NB * PER_B) * 2 > ws_size) NB >>= 1;

  u16* wbf = (u16*)d_ws;                    // Wq | Wk | Wv | Wp (bf16)
  u16* Wpb = wbf + 3 * 262144;

  const size_t slab = (size_t)NB * PER_B;
  u16* xbf  = wbf + WSEG;
  u16* y_ws = xbf + slab;

  cvt_w<<<dim3(256, 4), 256, 0, stream>>>(Wq, Wk, Wv, Wp, wbf);

  const int nslab = 16 / NB;
  for (int s = 0; s < nslab; ++s) {
    const float* x_s  = x   + (size_t)s * NB * PER_B;
    float*      out_s = out + (size_t)s * NB * PER_B;
    cvt_x<<<dim3(NB * 768), 256, 0, stream>>>(x_s, xbf);
    qkv_attn<<<dim3(NB * 48), 512, 0, stream>>>(xbf, wbf, bq, bk, bv, y_ws);
    gemm_bt<<<dim3(NB * 12, 4, 1), 256, 0, stream>>>(
        y_ws, Wpb, Wpb, Wpb, bp, bp, bp, nullptr, nullptr, nullptr, out_s, 0);
  }
}

// Round 8
// 203.461 us; speedup vs baseline: 4.4243x; 4.3252x over previous
//
#include <hip/hip_runtime.h>

// B=16, T=256, C=6, E=512, H=8, hd=64.
// Inputs fp32; OUTPUT fp32. Compute in bf16 MFMA; biases added in fp32.
//
// Round 12: fix rule-#20 violation introduced in round 10: the two-pass K/V
// loop `for (sc)` indexed acc[..][sc] and tiles[sc] with RUNTIME sc -> the
// whole 96-float accumulator went to scratch (FETCH 1.4 GB / WRITE 2.5 GB
// while VGPR_Count showed 76).  Fix: #pragma unroll on the sc loop so every
// acc index is compile-time.  Structure otherwise identical to round 11:
// 56 KB LDS (2 blocks/CU), two 128-key passes, launch_bounds(512,2).

typedef unsigned short u16;
typedef short bf16x8 __attribute__((ext_vector_type(8)));   // 8 bf16 = 4 VGPRs
typedef float f32x4 __attribute__((ext_vector_type(4)));
typedef u16 u16x4 __attribute__((ext_vector_type(4)));

#define MFMA16(a, b, c) __builtin_amdgcn_mfma_f32_16x16x32_bf16((a), (b), (c), 0, 0, 0)

__device__ __forceinline__ u16 f2b(float f) {
  union { float f; unsigned u; } v; v.f = f;
  unsigned r = v.u + 0x7fffu + ((v.u >> 16) & 1u);   // RNE (finite inputs)
  return (u16)(r >> 16);
}
__device__ __forceinline__ void gl_lds16(const void* g, void* l) {
  __builtin_amdgcn_global_load_lds(
      (const __attribute__((address_space(1))) void*)g,
      (__attribute__((address_space(3))) void*)l, 16, 0, 0);
}

// ---------------------------------------------------------------------------
// fp32 -> bf16 converters
// ---------------------------------------------------------------------------
__global__ void cvt_w(const float* W0, const float* W1, const float* W2,
                      const float* W3, u16* dst) {
  const float* src = (blockIdx.y == 0) ? W0 : (blockIdx.y == 1) ? W1
                   : (blockIdx.y == 2) ? W2 : W3;
  const int idx = (blockIdx.x * 256 + threadIdx.x) * 4;
  f32x4 v = *(const f32x4*)(src + idx);
  u16x4 o; o.x = f2b(v.x); o.y = f2b(v.y); o.z = f2b(v.z); o.w = f2b(v.w);
  *(u16x4*)(dst + (size_t)blockIdx.y * 262144 + idx) = o;
}

__global__ void cvt_x(const float* __restrict__ src, u16* __restrict__ dst) {
  const size_t idx = ((size_t)blockIdx.x * 256 + threadIdx.x) * 4;
  f32x4 v = *(const f32x4*)(src + idx);
  u16x4 o; o.x = f2b(v.x); o.y = f2b(v.y); o.z = f2b(v.z); o.w = f2b(v.w);
  *(u16x4*)(dst + idx) = o;
}

// ---------------------------------------------------------------------------
// Fused QKV + causal attention.  One block per (b,h,c); 512 thr = 8 waves.
// Wave w owns t-tiles {w, 15-w}.  LDS = 56 KB total (2 blocks/CU):
//   Phase 3 (two 128-key passes):
//     bytes [    0, 16384)  Ks  128 rows x 128 B  (XOR-swizzled)
//     bytes [16384, 32768)  Vts  64 rows x 256 B  (V^T, XOR-swizzled)
//     bytes [32768, 49152)  Qs   8 waves x 16 rows x 128 B (Q then P scratch)
//   Phase 1 staging: 2 x 28 KB at [0, 57344), aliases everything (disjoint
//   in time, barrier-separated).
// ---------------------------------------------------------------------------
#define STAGE(k, bi) do { \
  _Pragma("unroll") \
  for (int j_ = 0; j_ < 4; ++j_) \
    if (j_ < 3 || tid < 256) \
      gl_lds16(gsrc[j_] + (k) * 64, Sb + (bi) * 28672 + fl[j_]); \
} while (0)

__global__ __launch_bounds__(512, 2) void qkv_attn(
    const u16* __restrict__ xbf, const u16* __restrict__ wbf,
    const float* __restrict__ bq, const float* __restrict__ bk,
    const float* __restrict__ bv, u16* __restrict__ y_ws)
{
  const int blk = blockIdx.x;            // (b*8 + h)*6 + c  (b slab-local)
  const int b   = blk / 48;
  const int h   = (blk / 6) % 8;
  const int c   = blk % 6;

  __shared__ u16 LDS[28672];             // 56 KB
  char* Ksb  = (char*)LDS;               // Ks base   (16 KB)
  char* Vtsb = (char*)LDS + 16384;       // Vts base  (16 KB)
  char* Sb   = (char*)LDS;               // staging base (aliases all)

  const int tid  = threadIdx.x;
  const int lane = tid & 63;
  const int wv   = tid >> 6;
  const int r    = lane & 15;
  const int qd   = lane >> 4;
  const int tiles[2] = { wv, 15 - wv };
  char* Qw = (char*)LDS + 32768 + wv * 2048;   // per-wave 16 x 128 B

  // ---- staging source pointers (round-0 chunk swizzle: stored chunk q holds
  // global chunk (q - row>>1)&3; read side uses (qd + row>>1)&3) ----
  const char* gsrc[4]; int fl[4];
  #pragma unroll
  for (int j = 0; j < 4; ++j) {
    const int idx  = j * 512 + tid;
    const int flat = idx * 16;
    const int row  = flat >> 6;                       // 64 B per row
    const int gc   = (((flat >> 4) & 3) - (row >> 1)) & 3;
    fl[j] = flat;
    if (row < 256) {
      gsrc[j] = (const char*)xbf +
                ((size_t)(b * 256 + row) * 6 + c) * 1024 + gc * 16;
    } else {
      const int wr  = row - 256;
      const int tau = (wr >> 6) & 3;                  // masked for inactive lanes
      const int n   = wr & 63;
      gsrc[j] = (const char*)wbf + (size_t)tau * 524288 +
                (size_t)(h * 64 + n) * 1024 + gc * 16;
    }
  }

  // fragment LDS byte offsets within one staging buffer (loop-invariant)
  int aoff[2], boff[3][4];
  #pragma unroll
  for (int ti = 0; ti < 2; ++ti) {
    const int row = tiles[ti] * 16 + r;
    aoff[ti] = row * 64 + ((qd + (row >> 1)) & 3) * 16;
  }
  #pragma unroll
  for (int tau = 0; tau < 3; ++tau)
    #pragma unroll
    for (int nt = 0; nt < 4; ++nt) {
      const int row = 256 + tau * 64 + nt * 16 + r;
      boff[tau][nt] = row * 64 + ((qd + (row >> 1)) & 3) * 16;
    }

  f32x4 acc[3][2][4] = {};   // [q,k,v][tile][ntile]

  // ---- Phase 1: GEMM over K=512, BK=32, double-buffered ----
  STAGE(0, 0);
  __syncthreads();

  #pragma unroll 2
  for (int kt = 0; kt < 16; ++kt) {
    const int bi = kt & 1;
    if (kt < 15) STAGE(kt + 1, bi ^ 1);

    bf16x8 af[2], bfr[3][4];
    #pragma unroll
    for (int ti = 0; ti < 2; ++ti)
      af[ti] = *(const bf16x8*)(Sb + bi * 28672 + aoff[ti]);
    #pragma unroll
    for (int tau = 0; tau < 3; ++tau)
      #pragma unroll
      for (int nt = 0; nt < 4; ++nt)
        bfr[tau][nt] = *(const bf16x8*)(Sb + bi * 28672 + boff[tau][nt]);

    #pragma unroll
    for (int tau = 0; tau < 3; ++tau)
      #pragma unroll
      for (int ti = 0; ti < 2; ++ti)
        #pragma unroll
        for (int nt = 0; nt < 4; ++nt)
          acc[tau][ti][nt] = MFMA16(af[ti], bfr[tau][nt], acc[tau][ti][nt]);

    __syncthreads();   // drains staged kt+1; guards buffer reuse
  }
  // Phase-1 done: staging region free for Ks/Vts/Qs.

  // ---- biases (fp32) ----
  float bqv[4], bkv[4], bvv[4];
  #pragma unroll
  for (int nt = 0; nt < 4; ++nt) {
    const int col = h * 64 + nt * 16 + r;
    bqv[nt] = bq[col]; bkv[nt] = bk[col]; bvv[nt] = bv[col];
  }

  const int lo0 = ( qd      ^ (r & 7)) << 4;   // K/Q/P granule, kc=0
  const int lo1 = ((4 + qd) ^ (r & 7)) << 4;   // kc=1

  f32x4 o_acc[2][4] = {};
  float l_acc[2][4] = {{0.f,0.f,0.f,0.f},{0.f,0.f,0.f,0.f}};

  // ---- Phases 2+3: two 128-key passes (sc UNROLLED: all acc indices
  // compile-time -> accumulators stay in registers; rule #20) ----
  #pragma unroll
  for (int sc = 0; sc < 2; ++sc) {
    if (sc) __syncthreads();           // pass-0 reads done before overwrite

    // write this pass's K/V chunk from registers (tile tiles[sc])
    #pragma unroll
    for (int nt = 0; nt < 4; ++nt)
      #pragma unroll
      for (int rr = 0; rr < 4; ++rr) {
        const int tl = tiles[sc] * 16 + qd * 4 + rr - sc * 128;   // 0..127
        // Ks[tl][nt*16+r], 128-B rows, granule ^= tl&7
        const int kb = tl * 128 +
            (((nt * 2 + (r >> 3)) ^ (tl & 7)) << 4) + (r & 7) * 2;
        *(u16*)(Ksb + kb) = f2b(acc[1][sc][nt][rr] + bkv[nt]);
        // Vts[d = nt*16+r][t = tl], 256-B rows, granule ^= d&7 (= r&7)
        const int vb = (nt * 16 + r) * 256 +
            (((tl >> 3) ^ (r & 7)) << 4) + (tl & 7) * 2;
        *(u16*)(Vtsb + vb) = f2b(acc[2][sc][nt][rr] + bvv[nt]);
      }
    __syncthreads();

    // attention against this pass's keys
    #pragma unroll
    for (int ti = 0; ti < 2; ++ti) {
      if (sc == 1 && ti == 0) continue;   // q-tiles 0..7 complete in pass 0
      const int mt  = tiles[ti];
      const int i0  = mt * 16;
      const int nch = (mt >> 2) + 1;      // total 64-chunks this tile needs

      // Q bounce through per-wave scratch (wave-local; DS ops in-order)
      #pragma unroll
      for (int nt = 0; nt < 4; ++nt)
        #pragma unroll
        for (int rr = 0; rr < 4; ++rr) {
          const int prow = qd * 4 + rr;
          const int qb = prow * 128 +
              (((nt * 2 + (r >> 3)) ^ (prow & 7)) << 4) + (r & 7) * 2;
          *(u16*)(Qw + qb) = f2b(acc[0][ti][nt][rr] + bqv[nt]);
        }
      asm volatile("s_waitcnt lgkmcnt(0)" ::: "memory");

      bf16x8 qf[2];
      qf[0] = *(const bf16x8*)(Qw + r * 128 + lo0);
      qf[1] = *(const bf16x8*)(Qw + r * 128 + lo1);
      asm volatile("s_waitcnt lgkmcnt(0)" ::: "memory");

      #pragma unroll
      for (int jcl = 0; jcl < 2; ++jcl) {
        const int jcg = sc * 2 + jcl;
        if (jcg >= nch) continue;         // wave-uniform skip
        const int j0l = jcl * 64;         // key offset within this pass
        const int j0g = jcg * 64;         // global key offset (causal mask)

        f32x4 s[4] = {};
        #pragma unroll
        for (int nt = 0; nt < 4; ++nt) {
          const int krow = j0l + nt * 16 + r;
          bf16x8 kf0 = *(const bf16x8*)(Ksb + krow * 128 + lo0);
          s[nt] = MFMA16(qf[0], kf0, s[nt]);
          bf16x8 kf1 = *(const bf16x8*)(Ksb + krow * 128 + lo1);
          s[nt] = MFMA16(qf[1], kf1, s[nt]);
        }

        #pragma unroll
        for (int nt = 0; nt < 4; ++nt)
          #pragma unroll
          for (int rr = 0; rr < 4; ++rr) {
            const int i = i0 + qd * 4 + rr;
            const int j = j0g + nt * 16 + r;
            float p = __builtin_exp2f(fminf(s[nt][rr], 500.f) *
                                      0.1803368801111244f);  // *(1/8)*log2(e)
            if (j > i) p = 0.f;
            l_acc[ti][rr] += p;
            const int prow = qd * 4 + rr;
            const int pb = prow * 128 +
                (((nt * 2 + (r >> 3)) ^ (prow & 7)) << 4) + (r & 7) * 2;
            *(u16*)(Qw + pb) = f2b(p);
          }
        asm volatile("s_waitcnt lgkmcnt(0)" ::: "memory");

        bf16x8 pf[2];
        pf[0] = *(const bf16x8*)(Qw + r * 128 + lo0);
        pf[1] = *(const bf16x8*)(Qw + r * 128 + lo1);
        #pragma unroll
        for (int ntd = 0; ntd < 4; ++ntd) {
          const int vrow = ntd * 16 + r;
          bf16x8 vf0 = *(const bf16x8*)(Vtsb + vrow * 256 +
              ((((j0l >> 3) + qd) ^ (r & 7)) << 4));
          o_acc[ti][ntd] = MFMA16(pf[0], vf0, o_acc[ti][ntd]);
          bf16x8 vf1 = *(const bf16x8*)(Vtsb + vrow * 256 +
              ((((j0l >> 3) + 4 + qd) ^ (r & 7)) << 4));
          o_acc[ti][ntd] = MFMA16(pf[1], vf1, o_acc[ti][ntd]);
        }
      }
    }
  }

  // ---- output: y layout [b][t][h][c][d] (faithful to the torch reshape) ----
  const size_t obase = ((size_t)b * 256) * 3072 + h * 384 + c * 64;
  #pragma unroll
  for (int ti = 0; ti < 2; ++ti) {
    const int i0 = tiles[ti] * 16;
    float linv[4];
    #pragma unroll
    for (int rr = 0; rr < 4; ++rr) {
      float sum = l_acc[ti][rr];
      sum += __shfl_xor(sum, 1, 16);
      sum += __shfl_xor(sum, 2, 16);
      sum += __shfl_xor(sum, 4, 16);
      sum += __shfl_xor(sum, 8, 16);
      linv[rr] = 1.f / sum;
    }
    #pragma unroll
    for (int ntd = 0; ntd < 4; ++ntd)
      #pragma unroll
      for (int rr = 0; rr < 4; ++rr) {
        const int t = i0 + qd * 4 + rr;
        const int d = ntd * 16 + r;
        y_ws[obase + (size_t)t * 3072 + d] = f2b(o_acc[ti][ntd][rr] * linv[rr]);
      }
  }
}

// ---------------------------------------------------------------------------
// BT-GEMM (round-0 verbatim, used for the output projection only).
// ---------------------------------------------------------------------------
__global__ __launch_bounds__(256, 3) void gemm_bt(
    const u16* __restrict__ A,
    const u16* W0, const u16* W1, const u16* W2,
    const float* bs0, const float* bs1, const float* bs2,
    u16* O0, u16* O1, u16* O2,
    float* OF,
    int qkv_mode)
{
  const int z = blockIdx.z;
  const u16* W    = (z == 0) ? W0 : (z == 1) ? W1 : W2;
  const float* bs = (z == 0) ? bs0 : (z == 1) ? bs1 : bs2;
  u16* O          = (z == 0) ? O0 : (z == 1) ? O1 : O2;

  const int m0 = blockIdx.x * 128;
  const int n0 = blockIdx.y * 128;

  __shared__ u16 As[128 * 32];   // 8 KB, 64B rows, chunk swizzle (q + (row>>1)) & 3
  __shared__ u16 Bs[128 * 32];

  const int tid  = threadIdx.x;
  const int lane = tid & 63;
  const int wv   = tid >> 6;
  const int r    = lane & 15;
  const int qd   = lane >> 4;
  const int wm   = (wv & 1) * 64;
  const int wn   = (wv >> 1) * 64;

  f32x4 acc[4][4] = {};

  for (int k0 = 0; k0 < 512; k0 += 32) {
    __syncthreads();
    #pragma unroll
    for (int it = 0; it < 2; ++it) {
      const int flat = (it * 256 + tid) * 16;       // byte offset in 8KB tile
      const int row  = flat >> 6;                   // 64 B per row
      const int swc  = (flat >> 4) & 3;
      const int gc   = (swc - (row >> 1)) & 3;      // un-swizzle for global side
      gl_lds16((const char*)A + (size_t)(m0 + row) * 1024 + k0 * 2 + gc * 16,
               (char*)As + flat);
      gl_lds16((const char*)W + (size_t)(n0 + row) * 1024 + k0 * 2 + gc * 16,
               (char*)Bs + flat);
    }
    __syncthreads();

    bf16x8 af[4], bf[4];
    #pragma unroll
    for (int mt = 0; mt < 4; ++mt) {
      const int row = wm + mt * 16 + r;
      const int sw  = (qd + (row >> 1)) & 3;
      af[mt] = *(const bf16x8*)((const char*)As + row * 64 + sw * 16);
    }
    #pragma unroll
    for (int nt = 0; nt < 4; ++nt) {
      const int row = wn + nt * 16 + r;
      const int sw  = (qd + (row >> 1)) & 3;
      bf[nt] = *(const bf16x8*)((const char*)Bs + row * 64 + sw * 16);
    }
    #pragma unroll
    for (int mt = 0; mt < 4; ++mt)
      #pragma unroll
      for (int nt = 0; nt < 4; ++nt)
        acc[mt][nt] = MFMA16(af[mt], bf[nt], acc[mt][nt]);
  }

  float bv[4];
  #pragma unroll
  for (int nt = 0; nt < 4; ++nt) bv[nt] = bs[n0 + wn + nt * 16 + r];

  if (qkv_mode) {
    #pragma unroll
    for (int mt = 0; mt < 4; ++mt) {
      #pragma unroll
      for (int rr = 0; rr < 4; ++rr) {
        const int m   = m0 + wm + mt * 16 + qd * 4 + rr;   // (b*T+t)*C + c
        const int b   = m / 1536;
        const int rem = m - b * 1536;
        const int t   = rem / 6;
        const int c   = rem - t * 6;
        #pragma unroll
        for (int nt = 0; nt < 4; ++nt) {
          const int f = n0 + wn + nt * 16 + r;             // h*64 + d
          const int hh = f >> 6;
          const int d = f & 63;
          const size_t addr = ((((size_t)b * 8 + hh) * 6 + c) * 256 + t) * 64 + d;
          O[addr] = f2b(acc[mt][nt][rr] + bv[nt]);
        }
      }
    }
  } else {
    #pragma unroll
    for (int mt = 0; mt < 4; ++mt) {
      #pragma unroll
      for (int rr = 0; rr < 4; ++rr) {
        const int m = m0 + wm + mt * 16 + qd * 4 + rr;
        #pragma unroll
        for (int nt = 0; nt < 4; ++nt) {
          const int f = n0 + wn + nt * 16 + r;
          OF[(size_t)m * 512 + f] = acc[mt][nt][rr] + bv[nt];   // fp32 output
        }
      }
    }
  }
}

// ---------------------------------------------------------------------------
extern "C" void kernel_launch(void* const* d_in, const int* in_sizes, int n_in,
                              void* d_out, int out_size, void* d_ws, size_t ws_size,
                              hipStream_t stream) {
  const float* x  = (const float*)d_in[0];
  const float* Wq = (const float*)d_in[1];
  const float* bq = (const float*)d_in[2];
  const float* Wk = (const float*)d_in[3];
  const float* bk = (const float*)d_in[4];
  const float* Wv = (const float*)d_in[5];
  const float* bv = (const float*)d_in[6];
  const float* Wp = (const float*)d_in[7];
  const float* bp = (const float*)d_in[8];
  float* out = (float*)d_out;                        // fp32 output

  const size_t PER_B = 256 * 6 * 512;       // 786432 elems per tensor per batch
  const size_t WSEG  = 4 * 262144;          // converted weights: Wq,Wk,Wv,Wp

  int NB = 16;
  while (NB > 1 && (WSEG + (size_t)2 * NB * PER_B) * 2 > ws_size) NB >>= 1;

  u16* wbf = (u16*)d_ws;                    // Wq | Wk | Wv | Wp (bf16)
  u16* Wpb = wbf + 3 * 262144;

  const size_t slab = (size_t)NB * PER_B;
  u16* xbf  = wbf + WSEG;
  u16* y_ws = xbf + slab;

  cvt_w<<<dim3(256, 4), 256, 0, stream>>>(Wq, Wk, Wv, Wp, wbf);

  const int nslab = 16 / NB;
  for (int s = 0; s < nslab; ++s) {
    const float* x_s  = x   + (size_t)s * NB * PER_B;
    float*      out_s = out + (size_t)s * NB * PER_B;
    cvt_x<<<dim3(NB * 768), 256, 0, stream>>>(x_s, xbf);
    qkv_attn<<<dim3(NB * 48), 512, 0, stream>>>(xbf, wbf, bq, bk, bv, y_ws);
    gemm_bt<<<dim3(NB * 12, 4, 1), 256, 0, stream>>>(
        y_ws, Wpb, Wpb, Wpb, bp, bp, bp, nullptr, nullptr, nullptr, out_s, 0);
  }
}

// Round 9
// 202.015 us; speedup vs baseline: 4.4560x; 1.0072x over previous
//
#include <hip/hip_runtime.h>

// B=16, T=256, C=6, E=512, H=8, hd=64.
// Inputs fp32; OUTPUT fp32. Compute in bf16 MFMA; biases added in fp32.
//
// Round 13: residency is register-gated at 1 block/CU (92 VGPR + ~96 AGPR on
// the unified file -> 2 waves/SIMD; the 96 f32/thread Q+K+V accumulator is
// arithmetically irreducible), so stop chasing occupancy and remove the
// exposed latency instead:
//  - Phase 1 staging triple-buffered (3 x 28 KB, aliased over attn region),
//    loop-top wait = counted vmcnt(3) + raw s_barrier (never a full drain in
//    the steady state; vmcnt(0) only at the last K-step).  At 1-block
//    residency there is no TLP to hide the old per-iteration vmcnt(0) drain
//    (~400-700 cy x 16) -- this is the regime where counted vmcnt pays.
//  - Vts epilogue writes packed to b64 (rr=0..3 are consecutive bytes).
//  - cvt_w merged into cvt_x (one fewer launch).

typedef unsigned short u16;
typedef short bf16x8 __attribute__((ext_vector_type(8)));   // 8 bf16 = 4 VGPRs
typedef float f32x4 __attribute__((ext_vector_type(4)));
typedef u16 u16x4 __attribute__((ext_vector_type(4)));

#define MFMA16(a, b, c) __builtin_amdgcn_mfma_f32_16x16x32_bf16((a), (b), (c), 0, 0, 0)

__device__ __forceinline__ u16 f2b(float f) {
  union { float f; unsigned u; } v; v.f = f;
  unsigned r = v.u + 0x7fffu + ((v.u >> 16) & 1u);   // RNE (finite inputs)
  return (u16)(r >> 16);
}
__device__ __forceinline__ void gl_lds16(const void* g, void* l) {
  __builtin_amdgcn_global_load_lds(
      (const __attribute__((address_space(1))) void*)g,
      (__attribute__((address_space(3))) void*)l, 16, 0, 0);
}

// ---------------------------------------------------------------------------
// fp32 -> bf16 converter: blocks [0,nxb) convert x, blocks [nxb,nxb+1024)
// convert the four weight matrices (256 blocks each).
// ---------------------------------------------------------------------------
__global__ void cvt_all(const float* __restrict__ x, u16* __restrict__ xdst,
                        const float* W0, const float* W1, const float* W2,
                        const float* W3, u16* __restrict__ wdst, int nxb) {
  const int bx = blockIdx.x;
  if (bx < nxb) {
    const size_t idx = ((size_t)bx * 256 + threadIdx.x) * 4;
    f32x4 v = *(const f32x4*)(x + idx);
    u16x4 o; o.x = f2b(v.x); o.y = f2b(v.y); o.z = f2b(v.z); o.w = f2b(v.w);
    *(u16x4*)(xdst + idx) = o;
  } else {
    const int wb = bx - nxb;
    const float* src = (wb < 256) ? W0 : (wb < 512) ? W1
                     : (wb < 768) ? W2 : W3;
    const int idx = ((wb & 255) * 256 + threadIdx.x) * 4;
    f32x4 v = *(const f32x4*)(src + idx);
    u16x4 o; o.x = f2b(v.x); o.y = f2b(v.y); o.z = f2b(v.z); o.w = f2b(v.w);
    *(u16x4*)(wdst + (size_t)(wb >> 8) * 262144 + idx) = o;
  }
}

// ---------------------------------------------------------------------------
// Fused QKV + causal attention.  One block per (b,h,c); 512 thr = 8 waves.
// Wave w owns t-tiles {w, 15-w}.  LDS = 84 KB (1 block/CU, register-gated):
//   Phase 1 staging: 3 x 28 KB at [0, 86016), counted-vmcnt pipeline.
//   Phases 2-3 (two 128-key passes, alias staging bufs 0/1):
//     bytes [    0, 16384)  Ks  128 rows x 128 B  (XOR-swizzled)
//     bytes [16384, 32768)  Vts  64 rows x 256 B  (V^T, XOR-swizzled)
//     bytes [32768, 49152)  Qs   8 waves x 16 rows x 128 B (Q then P scratch)
// ---------------------------------------------------------------------------
#define STAGE(k, bi) do { \
  char* Sd_ = Sb + (bi) * 28672; \
  _Pragma("unroll") \
  for (int j_ = 0; j_ < 4; ++j_) \
    if (j_ < 3 || tid < 256) \
      gl_lds16(gsrc[j_] + (k) * 64, Sd_ + fl[j_]); \
} while (0)

__global__ __launch_bounds__(512, 2) void qkv_attn(
    const u16* __restrict__ xbf, const u16* __restrict__ wbf,
    const float* __restrict__ bq, const float* __restrict__ bk,
    const float* __restrict__ bv, u16* __restrict__ y_ws)
{
  const int blk = blockIdx.x;            // (b*8 + h)*6 + c  (b slab-local)
  const int b   = blk / 48;
  const int h   = (blk / 6) % 8;
  const int c   = blk % 6;

  __shared__ u16 LDS[43008];             // 84 KB
  char* Ksb  = (char*)LDS;               // Ks base   (16 KB)
  char* Vtsb = (char*)LDS + 16384;       // Vts base  (16 KB)
  char* Sb   = (char*)LDS;               // staging base (3 x 28 KB)

  const int tid  = threadIdx.x;
  const int lane = tid & 63;
  const int wv   = tid >> 6;
  const int r    = lane & 15;
  const int qd   = lane >> 4;
  const int tiles[2] = { wv, 15 - wv };
  char* Qw = (char*)LDS + 32768 + wv * 2048;   // per-wave 16 x 128 B

  // ---- staging source pointers (round-0 chunk swizzle: stored chunk q holds
  // global chunk (q - row>>1)&3; read side uses (qd + row>>1)&3) ----
  const char* gsrc[4]; int fl[4];
  #pragma unroll
  for (int j = 0; j < 4; ++j) {
    const int idx  = j * 512 + tid;
    const int flat = idx * 16;
    const int row  = flat >> 6;                       // 64 B per row
    const int gc   = (((flat >> 4) & 3) - (row >> 1)) & 3;
    fl[j] = flat;
    if (row < 256) {
      gsrc[j] = (const char*)xbf +
                ((size_t)(b * 256 + row) * 6 + c) * 1024 + gc * 16;
    } else {
      const int wr  = row - 256;
      const int tau = (wr >> 6) & 3;                  // masked for inactive lanes
      const int n   = wr & 63;
      gsrc[j] = (const char*)wbf + (size_t)tau * 524288 +
                (size_t)(h * 64 + n) * 1024 + gc * 16;
    }
  }

  // fragment LDS byte offsets within one staging buffer (loop-invariant)
  int aoff[2], boff[3][4];
  #pragma unroll
  for (int ti = 0; ti < 2; ++ti) {
    const int row = tiles[ti] * 16 + r;
    aoff[ti] = row * 64 + ((qd + (row >> 1)) & 3) * 16;
  }
  #pragma unroll
  for (int tau = 0; tau < 3; ++tau)
    #pragma unroll
    for (int nt = 0; nt < 4; ++nt) {
      const int row = 256 + tau * 64 + nt * 16 + r;
      boff[tau][nt] = row * 64 + ((qd + (row >> 1)) & 3) * 16;
    }

  f32x4 acc[3][2][4] = {};   // [q,k,v][tile][ntile]

  // ---- Phase 1: GEMM over K=512, BK=32, TRIPLE-buffered counted pipeline.
  // Stage k lives in buffer k%3.  Loop top: vmcnt(3) guarantees stage kt
  // landed (stage kt+1's <=3-4 loads may fly); raw barrier; issue stage kt+2
  // (its buffer was last read in iter kt-1, all waves past the barrier).
  STAGE(0, 0);
  STAGE(1, 1);

  #pragma unroll 2
  for (int kt = 0; kt < 16; ++kt) {
    if (kt < 15) { asm volatile("s_waitcnt vmcnt(3)\n\ts_barrier" ::: "memory"); }
    else         { asm volatile("s_waitcnt vmcnt(0)\n\ts_barrier" ::: "memory"); }

    if (kt + 2 < 16) STAGE(kt + 2, (kt + 2) % 3);

    char* Sc = Sb + (kt % 3) * 28672;
    bf16x8 af[2], bfr[3][4];
    #pragma unroll
    for (int ti = 0; ti < 2; ++ti)
      af[ti] = *(const bf16x8*)(Sc + aoff[ti]);
    #pragma unroll
    for (int tau = 0; tau < 3; ++tau)
      #pragma unroll
      for (int nt = 0; nt < 4; ++nt)
        bfr[tau][nt] = *(const bf16x8*)(Sc + boff[tau][nt]);

    #pragma unroll
    for (int tau = 0; tau < 3; ++tau)
      #pragma unroll
      for (int ti = 0; ti < 2; ++ti)
        #pragma unroll
        for (int nt = 0; nt < 4; ++nt)
          acc[tau][ti][nt] = MFMA16(af[ti], bfr[tau][nt], acc[tau][ti][nt]);
  }
  __syncthreads();   // all waves done reading buf0 before K/V epilogue aliases

  // ---- biases (fp32) ----
  float bqv[4], bkv[4], bvv[4];
  #pragma unroll
  for (int nt = 0; nt < 4; ++nt) {
    const int col = h * 64 + nt * 16 + r;
    bqv[nt] = bq[col]; bkv[nt] = bk[col]; bvv[nt] = bv[col];
  }

  const int lo0 = ( qd      ^ (r & 7)) << 4;   // K/Q/P granule, kc=0
  const int lo1 = ((4 + qd) ^ (r & 7)) << 4;   // kc=1

  f32x4 o_acc[2][4] = {};
  float l_acc[2][4] = {{0.f,0.f,0.f,0.f},{0.f,0.f,0.f,0.f}};

  // ---- Phases 2+3: two 128-key passes (sc UNROLLED: rule #20) ----
  #pragma unroll
  for (int sc = 0; sc < 2; ++sc) {
    if (sc) __syncthreads();           // pass-0 reads done before overwrite

    // write this pass's K/V chunk from registers (tile tiles[sc])
    {
      const int tl0 = tiles[sc] * 16 + qd * 4 - sc * 128;   // 0..124, %4==0
      // V^T: for fixed nt, rr=0..3 land on consecutive bytes -> b64 store
      #pragma unroll
      for (int nt = 0; nt < 4; ++nt) {
        u16x4 pv;
        #pragma unroll
        for (int rr = 0; rr < 4; ++rr)
          ((u16*)&pv)[rr] = f2b(acc[2][sc][nt][rr] + bvv[nt]);
        const int vb = (nt * 16 + r) * 256 +
            (((tl0 >> 3) ^ (r & 7)) << 4) + (tl0 & 7) * 2;
        *(u16x4*)(Vtsb + vb) = pv;
      }
      // K: rows differ per rr -> scalar
      #pragma unroll
      for (int nt = 0; nt < 4; ++nt)
        #pragma unroll
        for (int rr = 0; rr < 4; ++rr) {
          const int tl = tl0 + rr;
          const int kb = tl * 128 +
              (((nt * 2 + (r >> 3)) ^ (tl & 7)) << 4) + (r & 7) * 2;
          *(u16*)(Ksb + kb) = f2b(acc[1][sc][nt][rr] + bkv[nt]);
        }
    }
    __syncthreads();

    // attention against this pass's keys
    #pragma unroll
    for (int ti = 0; ti < 2; ++ti) {
      if (sc == 1 && ti == 0) continue;   // q-tiles 0..7 complete in pass 0
      const int mt  = tiles[ti];
      const int i0  = mt * 16;
      const int nch = (mt >> 2) + 1;      // total 64-chunks this tile needs

      // Q bounce through per-wave scratch (wave-local; DS ops in-order)
      #pragma unroll
      for (int nt = 0; nt < 4; ++nt)
        #pragma unroll
        for (int rr = 0; rr < 4; ++rr) {
          const int prow = qd * 4 + rr;
          const int qb = prow * 128 +
              (((nt * 2 + (r >> 3)) ^ (prow & 7)) << 4) + (r & 7) * 2;
          *(u16*)(Qw + qb) = f2b(acc[0][ti][nt][rr] + bqv[nt]);
        }
      asm volatile("s_waitcnt lgkmcnt(0)" ::: "memory");

      bf16x8 qf[2];
      qf[0] = *(const bf16x8*)(Qw + r * 128 + lo0);
      qf[1] = *(const bf16x8*)(Qw + r * 128 + lo1);
      asm volatile("s_waitcnt lgkmcnt(0)" ::: "memory");

      #pragma unroll
      for (int jcl = 0; jcl < 2; ++jcl) {
        const int jcg = sc * 2 + jcl;
        if (jcg >= nch) continue;         // wave-uniform skip
        const int j0l = jcl * 64;         // key offset within this pass
        const int j0g = jcg * 64;         // global key offset (causal mask)

        f32x4 s[4] = {};
        #pragma unroll
        for (int nt = 0; nt < 4; ++nt) {
          const int krow = j0l + nt * 16 + r;
          bf16x8 kf0 = *(const bf16x8*)(Ksb + krow * 128 + lo0);
          s[nt] = MFMA16(qf[0], kf0, s[nt]);
          bf16x8 kf1 = *(const bf16x8*)(Ksb + krow * 128 + lo1);
          s[nt] = MFMA16(qf[1], kf1, s[nt]);
        }

        #pragma unroll
        for (int nt = 0; nt < 4; ++nt)
          #pragma unroll
          for (int rr = 0; rr < 4; ++rr) {
            const int i = i0 + qd * 4 + rr;
            const int j = j0g + nt * 16 + r;
            float p = __builtin_exp2f(fminf(s[nt][rr], 500.f) *
                                      0.1803368801111244f);  // *(1/8)*log2(e)
            if (j > i) p = 0.f;
            l_acc[ti][rr] += p;
            const int prow = qd * 4 + rr;
            const int pb = prow * 128 +
                (((nt * 2 + (r >> 3)) ^ (prow & 7)) << 4) + (r & 7) * 2;
            *(u16*)(Qw + pb) = f2b(p);
          }
        asm volatile("s_waitcnt lgkmcnt(0)" ::: "memory");

        bf16x8 pf[2];
        pf[0] = *(const bf16x8*)(Qw + r * 128 + lo0);
        pf[1] = *(const bf16x8*)(Qw + r * 128 + lo1);
        #pragma unroll
        for (int ntd = 0; ntd < 4; ++ntd) {
          const int vrow = ntd * 16 + r;
          bf16x8 vf0 = *(const bf16x8*)(Vtsb + vrow * 256 +
              ((((j0l >> 3) + qd) ^ (r & 7)) << 4));
          o_acc[ti][ntd] = MFMA16(pf[0], vf0, o_acc[ti][ntd]);
          bf16x8 vf1 = *(const bf16x8*)(Vtsb + vrow * 256 +
              ((((j0l >> 3) + 4 + qd) ^ (r & 7)) << 4));
          o_acc[ti][ntd] = MFMA16(pf[1], vf1, o_acc[ti][ntd]);
        }
      }
    }
  }

  // ---- output: y layout [b][t][h][c][d] (faithful to the torch view) ----
  const size_t obase = ((size_t)b * 256) * 3072 + h * 384 + c * 64;
  #pragma unroll
  for (int ti = 0; ti < 2; ++ti) {
    const int i0 = tiles[ti] * 16;
    float linv[4];
    #pragma unroll
    for (int rr = 0; rr < 4; ++rr) {
      float sum = l_acc[ti][rr];
      sum += __shfl_xor(sum, 1, 16);
      sum += __shfl_xor(sum, 2, 16);
      sum += __shfl_xor(sum, 4, 16);
      sum += __shfl_xor(sum, 8, 16);
      linv[rr] = 1.f / sum;
    }
    #pragma unroll
    for (int ntd = 0; ntd < 4; ++ntd)
      #pragma unroll
      for (int rr = 0; rr < 4; ++rr) {
        const int t = i0 + qd * 4 + rr;
        const int d = ntd * 16 + r;
        y_ws[obase + (size_t)t * 3072 + d] = f2b(o_acc[ti][ntd][rr] * linv[rr]);
      }
  }
}

// ---------------------------------------------------------------------------
// BT-GEMM (round-0 verbatim, used for the output projection only).
// ---------------------------------------------------------------------------
__global__ __launch_bounds__(256, 3) void gemm_bt(
    const u16* __restrict__ A,
    const u16* W0, const u16* W1, const u16* W2,
    const float* bs0, const float* bs1, const float* bs2,
    u16* O0, u16* O1, u16* O2,
    float* OF,
    int qkv_mode)
{
  const int z = blockIdx.z;
  const u16* W    = (z == 0) ? W0 : (z == 1) ? W1 : W2;
  const float* bs = (z == 0) ? bs0 : (z == 1) ? bs1 : bs2;
  u16* O          = (z == 0) ? O0 : (z == 1) ? O1 : O2;

  const int m0 = blockIdx.x * 128;
  const int n0 = blockIdx.y * 128;

  __shared__ u16 As[128 * 32];   // 8 KB, 64B rows, chunk swizzle (q + (row>>1)) & 3
  __shared__ u16 Bs[128 * 32];

  const int tid  = threadIdx.x;
  const int lane = tid & 63;
  const int wv   = tid >> 6;
  const int r    = lane & 15;
  const int qd   = lane >> 4;
  const int wm   = (wv & 1) * 64;
  const int wn   = (wv >> 1) * 64;

  f32x4 acc[4][4] = {};

  for (int k0 = 0; k0 < 512; k0 += 32) {
    __syncthreads();
    #pragma unroll
    for (int it = 0; it < 2; ++it) {
      const int flat = (it * 256 + tid) * 16;       // byte offset in 8KB tile
      const int row  = flat >> 6;                   // 64 B per row
      const int swc  = (flat >> 4) & 3;
      const int gc   = (swc - (row >> 1)) & 3;      // un-swizzle for global side
      gl_lds16((const char*)A + (size_t)(m0 + row) * 1024 + k0 * 2 + gc * 16,
               (char*)As + flat);
      gl_lds16((const char*)W + (size_t)(n0 + row) * 1024 + k0 * 2 + gc * 16,
               (char*)Bs + flat);
    }
    __syncthreads();

    bf16x8 af[4], bf[4];
    #pragma unroll
    for (int mt = 0; mt < 4; ++mt) {
      const int row = wm + mt * 16 + r;
      const int sw  = (qd + (row >> 1)) & 3;
      af[mt] = *(const bf16x8*)((const char*)As + row * 64 + sw * 16);
    }
    #pragma unroll
    for (int nt = 0; nt < 4; ++nt) {
      const int row = wn + nt * 16 + r;
      const int sw  = (qd + (row >> 1)) & 3;
      bf[nt] = *(const bf16x8*)((const char*)Bs + row * 64 + sw * 16);
    }
    #pragma unroll
    for (int mt = 0; mt < 4; ++mt)
      #pragma unroll
      for (int nt = 0; nt < 4; ++nt)
        acc[mt][nt] = MFMA16(af[mt], bf[nt], acc[mt][nt]);
  }

  float bv[4];
  #pragma unroll
  for (int nt = 0; nt < 4; ++nt) bv[nt] = bs[n0 + wn + nt * 16 + r];

  if (qkv_mode) {
    #pragma unroll
    for (int mt = 0; mt < 4; ++mt) {
      #pragma unroll
      for (int rr = 0; rr < 4; ++rr) {
        const int m   = m0 + wm + mt * 16 + qd * 4 + rr;   // (b*T+t)*C + c
        const int b   = m / 1536;
        const int rem = m - b * 1536;
        const int t   = rem / 6;
        const int c   = rem - t * 6;
        #pragma unroll
        for (int nt = 0; nt < 4; ++nt) {
          const int f = n0 + wn + nt * 16 + r;             // h*64 + d
          const int hh = f >> 6;
          const int d = f & 63;
          const size_t addr = ((((size_t)b * 8 + hh) * 6 + c) * 256 + t) * 64 + d;
          O[addr] = f2b(acc[mt][nt][rr] + bv[nt]);
        }
      }
    }
  } else {
    #pragma unroll
    for (int mt = 0; mt < 4; ++mt) {
      #pragma unroll
      for (int rr = 0; rr < 4; ++rr) {
        const int m = m0 + wm + mt * 16 + qd * 4 + rr;
        #pragma unroll
        for (int nt = 0; nt < 4; ++nt) {
          const int f = n0 + wn + nt * 16 + r;
          OF[(size_t)m * 512 + f] = acc[mt][nt][rr] + bv[nt];   // fp32 output
        }
      }
    }
  }
}

// ---------------------------------------------------------------------------
extern "C" void kernel_launch(void* const* d_in, const int* in_sizes, int n_in,
                              void* d_out, int out_size, void* d_ws, size_t ws_size,
                              hipStream_t stream) {
  const float* x  = (const float*)d_in[0];
  const float* Wq = (const float*)d_in[1];
  const float* bq = (const float*)d_in[2];
  const float* Wk = (const float*)d_in[3];
  const float* bk = (const float*)d_in[4];
  const float* Wv = (const float*)d_in[5];
  const float* bv = (const float*)d_in[6];
  const float* Wp = (const float*)d_in[7];
  const float* bp = (const float*)d_in[8];
  float* out = (float*)d_out;                        // fp32 output

  const size_t PER_B = 256 * 6 * 512;       // 786432 elems per tensor per batch
  const size_t WSEG  = 4 * 262144;          // converted weights: Wq,Wk,Wv,Wp

  int NB = 16;
  while (NB > 1 && (WSEG + (size_t)2 * NB * PER_B) * 2 > ws_size) NB >>= 1;

  u16* wbf = (u16*)d_ws;                    // Wq | Wk | Wv | Wp (bf16)
  u16* Wpb = wbf + 3 * 262144;

  const size_t slab = (size_t)NB * PER_B;
  u16* xbf  = wbf + WSEG;
  u16* y_ws = xbf + slab;

  const int nslab = 16 / NB;
  for (int s = 0; s < nslab; ++s) {
    const float* x_s  = x   + (size_t)s * NB * PER_B;
    float*      out_s = out + (size_t)s * NB * PER_B;
    const int nxb = NB * 768;
    const int grid = (s == 0) ? nxb + 1024 : nxb;   // weights once
    cvt_all<<<dim3(grid), 256, 0, stream>>>(x_s, xbf, Wq, Wk, Wv, Wp, wbf, nxb);
    qkv_attn<<<dim3(NB * 48), 512, 0, stream>>>(xbf, wbf, bq, bk, bv, y_ws);
    gemm_bt<<<dim3(NB * 12, 4, 1), 256, 0, stream>>>(
        y_ws, Wpb, Wpb, Wpb, bp, bp, bp, nullptr, nullptr, nullptr, out_s, 0);
  }
}